// Round 18
// baseline (204.784 us; speedup 1.0000x reference)
//
#include <hip/hip_runtime.h>
#include <hip/hip_fp16.h>

// InvariantGaussianAttention, MI355X (gfx950)
// B=2 N=384 CS=384 CZ=128 H=8 CH=16 G=2 P=8 CZ4=32
#define NB   2
#define NN   384
#define NCS  384
#define NCZ  128
#define NH   8
#define NCH  16
#define NG   2
#define NP   8
#define NCZ4 32
#define BN   (NB*NN)   // 768
#define LINW 768       // q(128)|k(128)|v(128)|qg(96)|kg(96)|vp(192)
#define PZROW ((size_t)BN*NN)   // 294912 half2 entries per c-pair row
#define NZP  1152      // persistent zproj blocks (4 chunks each)
#define NRB  288       // rowlin blocks, FIRST in grid

typedef _Float16 f16x8 __attribute__((ext_vector_type(8)));
typedef float    f32x4 __attribute__((ext_vector_type(4)));

typedef __attribute__((address_space(3))) char        as3_char;
typedef __attribute__((address_space(1))) const char  as1_char;
static __device__ __forceinline__ void gload_lds16(const void* g, void* l) {
    __builtin_amdgcn_global_load_lds((const as1_char*)g, (as3_char*)l, 16, 0, 0);
}

// ---------------- K0: build MFMA B-fragments of [Wb | Wdz | 0pad] (f16) -------------
__global__ void k_wprep(const float* __restrict__ Wb, const float* __restrict__ Wdz,
                        _Float16* __restrict__ wf) {
    int t = threadIdx.x;
    for (int e = t; e < 12*64*8; e += 256) {
        int r = e & 7, lane = (e >> 3) & 63, nk = e >> 9;
        int n = nk >> 2, kk = nk & 3;
        int c = kk*32 + (lane >> 4)*8 + r;
        int col = n*16 + (lane & 15);
        float w;
        if      (col < 8)  w = Wb[c*NH + col];
        else if (col < 40) w = Wdz[c*NCZ4 + (col-8)];
        else               w = 0.f;
        wf[e] = (_Float16)w;
    }
}

// per-iteration zproj body: fragments from zbuf, MFMA, scatter to outb, store.
static __device__ __forceinline__ void zchunk_body(
        const char* zbuf, char* outb, const f16x8* bfr,
        float b0, float b1, float b2,
        int t, int lane, int w, int ccol, int cjl, int bi, int ch,
        float* __restrict__ zbg, __half* __restrict__ pzg2) {
    float (*zbT)[64] = (float(*)[64])outb;
    __half (*pzt)[34] = (__half(*)[34])(outb + 2048);
    int row = w*16 + (lane & 15);
    int r7  = row & 7;
    const char* zrow_b = zbuf + row*512;
    f16x8 af[4];
    #pragma unroll
    for (int kk = 0; kk < 4; ++kk) {
        int u0 = ((lane >> 4) << 1) + kk*8;
        float4 lo = *(const float4*)(zrow_b + (((u0    ) ^ r7) << 4));
        float4 hi = *(const float4*)(zrow_b + (((u0 + 1) ^ r7) << 4));
        af[kk][0]=(_Float16)lo.x; af[kk][1]=(_Float16)lo.y;
        af[kk][2]=(_Float16)lo.z; af[kk][3]=(_Float16)lo.w;
        af[kk][4]=(_Float16)hi.x; af[kk][5]=(_Float16)hi.y;
        af[kk][6]=(_Float16)hi.z; af[kk][7]=(_Float16)hi.w;
    }
    f32x4 ac0 = {0.f,0.f,0.f,0.f}, ac1 = ac0, ac2 = ac0;
    ac0 = __builtin_amdgcn_mfma_f32_16x16x32_f16(af[0], bfr[0], ac0, 0,0,0);
    ac1 = __builtin_amdgcn_mfma_f32_16x16x32_f16(af[0], bfr[4], ac1, 0,0,0);
    ac2 = __builtin_amdgcn_mfma_f32_16x16x32_f16(af[0], bfr[8], ac2, 0,0,0);
    ac0 = __builtin_amdgcn_mfma_f32_16x16x32_f16(af[1], bfr[1], ac0, 0,0,0);
    ac1 = __builtin_amdgcn_mfma_f32_16x16x32_f16(af[1], bfr[5], ac1, 0,0,0);
    ac2 = __builtin_amdgcn_mfma_f32_16x16x32_f16(af[1], bfr[9], ac2, 0,0,0);
    ac0 = __builtin_amdgcn_mfma_f32_16x16x32_f16(af[2], bfr[2], ac0, 0,0,0);
    ac1 = __builtin_amdgcn_mfma_f32_16x16x32_f16(af[2], bfr[6], ac1, 0,0,0);
    ac2 = __builtin_amdgcn_mfma_f32_16x16x32_f16(af[2], bfr[10], ac2, 0,0,0);
    ac0 = __builtin_amdgcn_mfma_f32_16x16x32_f16(af[3], bfr[3], ac0, 0,0,0);
    ac1 = __builtin_amdgcn_mfma_f32_16x16x32_f16(af[3], bfr[7], ac1, 0,0,0);
    ac2 = __builtin_amdgcn_mfma_f32_16x16x32_f16(af[3], bfr[11], ac2, 0,0,0);
    #pragma unroll
    for (int r = 0; r < 4; ++r) {
        int j = cjl + r;
        float v0 = ac0[r] + b0;
        if (ccol < 8) zbT[ccol][j] = v0;
        else          pzt[j][ccol-8] = __float2half(v0);
        pzt[j][ccol+8] = __float2half(ac1[r] + b1);
        if (ccol < 8)
            pzt[j][ccol+24] = __float2half(ac2[r] + b2);
    }
    asm volatile("s_waitcnt lgkmcnt(0)" ::: "memory");
    __builtin_amdgcn_sched_barrier(0);
    __builtin_amdgcn_s_barrier();
    __builtin_amdgcn_sched_barrier(0);
    {   // zbT -> zbg[bi][h][ch*64 + j]
        int e = t*2, h = e >> 6, j = e & 63;
        float2 v; v.x = zbT[h][j]; v.y = zbT[h][j+1];
        *(float2*)(zbg + ((size_t)bi*NH + h)*NN + ch*64 + j) = v;
    }
    {   // pzt -> pzg2 (c-major half2, float4-packed)
        int cp = t >> 4, l = t & 15, j0 = l*4;
        union { __half2 h2[4]; float4 f4; } u;
        #pragma unroll
        for (int r = 0; r < 4; ++r) {
            int j = j0 + r;
            u.h2[r] = __halves2half2(pzt[j][2*cp], pzt[j][2*cp+1]);
        }
        __half2* dst = (__half2*)pzg2 + (size_t)cp*PZROW + (size_t)bi*NN + ch*64 + j0;
        *(float4*)dst = u.f4;
    }
}

static __device__ __forceinline__ void dma_chunk(const float* z, int c, int lane, int w,
                                                 char* dstbuf) {
    const char* nb = (const char*)(z + ((size_t)(c/6)*NN + (c%6)*64)*NCZ);
    #pragma unroll
    for (int i = 0; i < 8; ++i) {
        int o = (w*8 + i)*1024 + lane*16;
        int r = o >> 9;
        int u = (o >> 4) & 31;
        gload_lds16(nb + (r << 9) + ((u ^ (r & 7)) << 4), dstbuf + (w*8 + i)*1024);
    }
}

// ---------------- KA: role-switched { rowlin (0..287) | persistent DMA zproj } ------
__global__ void k_zrow(const float* __restrict__ z, const _Float16* __restrict__ wf,
       const float* __restrict__ bb, const float* __restrict__ bdz,
       const float* __restrict__ s,
       const float* __restrict__ Wq, const float* __restrict__ Wk,
       const float* __restrict__ Wv,
       const float* __restrict__ Wqg, const float* __restrict__ bqg,
       const float* __restrict__ Wkg, const float* __restrict__ bkg,
       const float* __restrict__ Wvp, const float* __restrict__ bvp,
       float* __restrict__ zbg, __half* __restrict__ pzg2,
       float* __restrict__ lin, float* __restrict__ kT, float* __restrict__ vT) {
    __shared__ __align__(16) char smem[78336];  // zsA 32K | zsB 32K | outA 6400 | outB 6400
    int t = threadIdx.x;

    if (blockIdx.x >= NRB) {
        // ================= persistent zproj, counted-vmcnt double buffer ==========
        int lane = t & 63, w = t >> 6;
        int ccol = lane & 15;
        int cjl  = w*16 + (lane >> 4)*4;
        int zbid = blockIdx.x - NRB;              // 0..1151

        dma_chunk(z, zbid, lane, w, smem);        // chunk 0 -> zsA

        f16x8 bfr[12];
        #pragma unroll
        for (int nk = 0; nk < 12; ++nk)
            bfr[nk] = ((const f16x8*)wf)[nk*64 + lane];
        float b0 = (ccol < 8) ? bb[ccol] : bdz[ccol - 8];
        float b1 = bdz[ccol + 8];
        float b2 = (ccol < 8) ? bdz[ccol + 24] : 0.f;

        // ---- iter 0: issue chunk1 -> zsB; wait only chunk0 (8 newer in flight) ----
        dma_chunk(z, zbid + NZP, lane, w, smem + 32768);
        asm volatile("s_waitcnt vmcnt(8)" ::: "memory");
        __builtin_amdgcn_sched_barrier(0);
        __builtin_amdgcn_s_barrier();
        __builtin_amdgcn_sched_barrier(0);
        zchunk_body(smem, smem + 65536, bfr, b0, b1, b2, t, lane, w, ccol, cjl,
                    zbid / 6, zbid % 6, zbg, pzg2);

        // ---- iter 1: issue chunk2 -> zsA; wait chunk1 (8 newer in flight) ----
        dma_chunk(z, zbid + 2*NZP, lane, w, smem);
        asm volatile("s_waitcnt vmcnt(8)" ::: "memory");
        __builtin_amdgcn_sched_barrier(0);
        __builtin_amdgcn_s_barrier();
        __builtin_amdgcn_sched_barrier(0);
        {
            int c = zbid + NZP;
            zchunk_body(smem + 32768, smem + 65536 + 6400, bfr, b0, b1, b2, t, lane, w,
                        ccol, cjl, c / 6, c % 6, zbg, pzg2);
        }

        // ---- iter 2: issue chunk3 -> zsB; wait chunk2 ----
        dma_chunk(z, zbid + 3*NZP, lane, w, smem + 32768);
        asm volatile("s_waitcnt vmcnt(8)" ::: "memory");
        __builtin_amdgcn_sched_barrier(0);
        __builtin_amdgcn_s_barrier();
        __builtin_amdgcn_sched_barrier(0);
        {
            int c = zbid + 2*NZP;
            zchunk_body(smem, smem + 65536, bfr, b0, b1, b2, t, lane, w,
                        ccol, cjl, c / 6, c % 6, zbg, pzg2);
        }

        // ---- iter 3: wait everything ----
        asm volatile("s_waitcnt vmcnt(0)" ::: "memory");
        __builtin_amdgcn_sched_barrier(0);
        __builtin_amdgcn_s_barrier();
        __builtin_amdgcn_sched_barrier(0);
        {
            int c = zbid + 3*NZP;
            zchunk_body(smem + 32768, smem + 65536 + 6400, bfr, b0, b1, b2, t, lane, w,
                        ccol, cjl, c / 6, c % 6, zbg, pzg2);
        }
    } else {
        // ================= rowlin (8 rows/block), 4x unrolled ILP =================
        float (*sl)[NCS] = (float(*)[NCS])smem;   // 12288 B
        int rb = blockIdx.x;                      // 0..287
        int r0 = (rb / 3) * 8;
        int col = (rb % 3) * 256 + t;
        for (int idx = t; idx < 8*NCS; idx += 256)
            sl[idx / NCS][idx % NCS] = s[(size_t)(r0 + idx/NCS)*NCS + (idx % NCS)];
        __syncthreads();
        const float* W; int sw; float bias = 0.f;
        if      (col < 128) { W = Wq  + col;        sw = 128; }
        else if (col < 256) { W = Wk  + (col-128);  sw = 128; }
        else if (col < 384) { W = Wv  + (col-256);  sw = 128; }
        else if (col < 480) { W = Wqg + (col-384);  sw = 96;  bias = bqg[col-384]; }
        else if (col < 576) { W = Wkg + (col-480);  sw = 96;  bias = bkg[col-480]; }
        else                { W = Wvp + (col-576);  sw = 192; bias = bvp[col-576]; }
        float a[8];
        #pragma unroll
        for (int r = 0; r < 8; ++r) a[r] = 0.f;
        #pragma unroll 1
        for (int c = 0; c < NCS; c += 4) {
            float w0 = W[(size_t)(c+0)*sw];
            float w1 = W[(size_t)(c+1)*sw];
            float w2 = W[(size_t)(c+2)*sw];
            float w3 = W[(size_t)(c+3)*sw];
            #pragma unroll
            for (int r = 0; r < 8; ++r) {
                a[r] = fmaf(sl[r][c+0], w0, a[r]);
                a[r] = fmaf(sl[r][c+1], w1, a[r]);
                a[r] = fmaf(sl[r][c+2], w2, a[r]);
                a[r] = fmaf(sl[r][c+3], w3, a[r]);
            }
        }
        #pragma unroll
        for (int r = 0; r < 8; ++r)
            lin[(size_t)(r0+r)*LINW + col] = a[r] + bias;
        if (col >= 128 && col < 384) {   // j-major panels for k_attn2
            f32x4 v0, v1;
            #pragma unroll
            for (int r = 0; r < 4; ++r) { v0[r] = a[r]; v1[r] = a[4+r]; }
            float* dst = (col < 256) ? (kT + (size_t)(col-128)*BN + r0)
                                     : (vT + (size_t)(col-256)*BN + r0);
            *(f32x4*)dst = v0;
            *(f32x4*)(dst+4) = v1;
        }
    }
}

// ---------------- K2: to_global; k-side + value points written j-major ----------------
__global__ void k_geom(const float* __restrict__ lin, const float* __restrict__ rot,
                       const float* __restrict__ trans, const float* __restrict__ lm,
                       const float* __restrict__ sc,
                       float* __restrict__ qmu, float* __restrict__ qsig,
                       float* __restrict__ kmuT, float* __restrict__ ksigT,
                       float* __restrict__ vpgT) {
    int bn = blockIdx.x, t = threadIdx.x;
    __shared__ float R[9], T[3], A[3], Bs[3];
    if (t < 9) R[t] = rot[bn*9 + t];
    if (t < 3) { T[t] = trans[bn*3+t]; A[t] = lm[bn*3+t]; Bs[t] = sc[bn*3+t]; }
    __syncthreads();
    {   // value points: one per thread (h=t/8, p=t&7), j-major out
        int h = t >> 3, p = t & 7;
        const float* vr = lin + (size_t)bn*LINW + 576 + h*24 + p*3;
        float x = vr[0], y = vr[1], z = vr[2];
        int e = h*24 + p*3;
        vpgT[(size_t)(e+0)*BN + bn] = R[0]*x + R[1]*y + R[2]*z + T[0];
        vpgT[(size_t)(e+1)*BN + bn] = R[3]*x + R[4]*y + R[5]*z + T[1];
        vpgT[(size_t)(e+2)*BN + bn] = R[6]*x + R[7]*y + R[8]*z + T[2];
    }
    if (t < 32) {
        int side = t >> 4, item = t & 15;      // item = h*2+g
        const float* raw = lin + (size_t)bn*LINW + (side ? 480 : 384) + item*6;
        float u0 = tanhf(raw[0])*3.f, u1 = tanhf(raw[1])*3.f, u2 = tanhf(raw[2])*3.f;
        float e0 = Bs[0] + tanhf(raw[3])*2.f;
        float e1 = Bs[1] + tanhf(raw[4])*2.f;
        float e2 = Bs[2] + tanhf(raw[5])*2.f;
        float sl0 = fmaxf(expf(e0), 1e-6f);
        float sl1 = fmaxf(expf(e1), 1e-6f);
        float sl2 = fmaxf(expf(e2), 1e-6f);
        float p0 = A[0] + u0*sl0, p1 = A[1] + u1*sl1, p2 = A[2] + u2*sl2;
        float mu0 = R[0]*p0 + R[1]*p1 + R[2]*p2 + T[0];
        float mu1 = R[3]*p0 + R[4]*p1 + R[5]*p2 + T[1];
        float mu2 = R[6]*p0 + R[7]*p1 + R[8]*p2 + T[2];
        float v0 = expf(2.f*e0), v1 = expf(2.f*e1), v2 = expf(2.f*e2);
        float s00 = R[0]*R[0]*v0 + R[1]*R[1]*v1 + R[2]*R[2]*v2;
        float s01 = R[0]*R[3]*v0 + R[1]*R[4]*v1 + R[2]*R[5]*v2;
        float s02 = R[0]*R[6]*v0 + R[1]*R[7]*v1 + R[2]*R[8]*v2;
        float s11 = R[3]*R[3]*v0 + R[4]*R[4]*v1 + R[5]*R[5]*v2;
        float s12 = R[3]*R[6]*v0 + R[4]*R[7]*v1 + R[5]*R[8]*v2;
        float s22 = R[6]*R[6]*v0 + R[7]*R[7]*v1 + R[8]*R[8]*v2;
        if (side) {   // k-side: j-major
            kmuT[(size_t)(item*3+0)*BN + bn] = mu0;
            kmuT[(size_t)(item*3+1)*BN + bn] = mu1;
            kmuT[(size_t)(item*3+2)*BN + bn] = mu2;
            ksigT[(size_t)(item*6+0)*BN + bn] = s00;
            ksigT[(size_t)(item*6+1)*BN + bn] = s01;
            ksigT[(size_t)(item*6+2)*BN + bn] = s02;
            ksigT[(size_t)(item*6+3)*BN + bn] = s11;
            ksigT[(size_t)(item*6+4)*BN + bn] = s12;
            ksigT[(size_t)(item*6+5)*BN + bn] = s22;
        } else {      // q-side: row-major (per-block broadcast read)
            float* mud = qmu + (size_t)bn*48 + item*3;
            mud[0]=mu0; mud[1]=mu1; mud[2]=mu2;
            float* sgd = qsig + (size_t)bn*96 + item*6;
            sgd[0]=s00; sgd[1]=s01; sgd[2]=s02; sgd[3]=s11; sgd[4]=s12; sgd[5]=s22;
        }
    }
}

// ---------------- K3: attention (no z), one block per (b,i), j-vectorized passes ----
__global__ void __launch_bounds__(256, 2)
k_attn2(const float* __restrict__ mask,
        const float* __restrict__ rot, const float* __restrict__ trans,
        const float* __restrict__ lin,
        const float* __restrict__ qmu, const float* __restrict__ qsig,
        const float* __restrict__ kmuT, const float* __restrict__ ksigT,
        const float* __restrict__ kT, const float* __restrict__ vT,
        const float* __restrict__ vpgT,
        const float* __restrict__ zbg, const __half* __restrict__ pzg2,
        const float* __restrict__ gsc, const float* __restrict__ gbi,
        float* __restrict__ cat) {
    __shared__ float  logits[NH][NN];   // 12 KB
    __shared__ float  qrow[128];
    __shared__ float  qmu_s[48], qsig_s[96];
    __shared__ float  Rm[9], Tv[3];
    __shared__ float  aH[NH], bH[NH];
    __shared__ float  maskI;

    int t  = threadIdx.x;
    int b  = blockIdx.x / NN, i = blockIdx.x % NN;
    int bi = b*NN + i;
    const size_t boff = (size_t)b*NN;

    if (t < 128) qrow[t] = lin[(size_t)bi*LINW + t];
    if (t < 48)  qmu_s[t] = qmu[(size_t)bi*48 + t];
    if (t >= 64 && t < 160) qsig_s[t-64] = qsig[(size_t)bi*96 + (t-64)];
    if (t >= 160 && t < 169) Rm[t-160] = rot[bi*9 + (t-160)];
    if (t >= 169 && t < 172) Tv[t-169] = trans[bi*3 + (t-169)];
    if (t >= 176 && t < 184) {
        int h = t-176;
        float x = gsc[h];
        aH[h] = (x > 20.f) ? x : log1pf(expf(x));
        bH[h] = gbi[h];
    }
    if (t == 255) maskI = mask[bi];
    __syncthreads();

    // ---- phase 0: qk + geo NLL + zb + mask; j-quad mapping, coalesced ----
    int h = t >> 5, lnn = t & 31;
    {
        float qv[16];
        #pragma unroll
        for (int d = 0; d < 16; ++d) qv[d] = qrow[h*16 + d];
        float qm[6], qs[12];
        #pragma unroll
        for (int e = 0; e < 6; ++e)  qm[e] = qmu_s[h*6 + e];
        #pragma unroll
        for (int e = 0; e < 12; ++e) qs[e] = qsig_s[h*12 + e];
        float ascale = aH[h], hbias = bH[h], mI = maskI;
        #pragma unroll 1
        for (int jj = 0; jj < 3; ++jj) {
            int j4 = jj*128 + lnn*4;
            const float* kp = kT + (size_t)(h*16)*BN + boff + j4;
            f32x4 qk = {0.f,0.f,0.f,0.f};
            #pragma unroll
            for (int d = 0; d < 16; ++d) {
                f32x4 kv = *(const f32x4*)(kp + (size_t)d*BN);
                #pragma unroll
                for (int r = 0; r < 4; ++r) qk[r] = fmaf(qv[d], kv[r], qk[r]);
            }
            f32x4 geo = {0.f,0.f,0.f,0.f};
            #pragma unroll
            for (int g = 0; g < NG; ++g) {
                const float* kmb = kmuT + (size_t)((h*2+g)*3)*BN + boff + j4;
                f32x4 km0 = *(const f32x4*)(kmb);
                f32x4 km1 = *(const f32x4*)(kmb + BN);
                f32x4 km2 = *(const f32x4*)(kmb + 2*BN);
                const float* ksb = ksigT + (size_t)((h*2+g)*6)*BN + boff + j4;
                f32x4 ks0 = *(const f32x4*)(ksb);
                f32x4 ks1 = *(const f32x4*)(ksb + BN);
                f32x4 ks2 = *(const f32x4*)(ksb + 2*BN);
                f32x4 ks3 = *(const f32x4*)(ksb + 3*BN);
                f32x4 ks4 = *(const f32x4*)(ksb + 4*BN);
                f32x4 ks5 = *(const f32x4*)(ksb + 5*BN);
                #pragma unroll
                for (int r = 0; r < 4; ++r) {
                    float d0 = qm[g*3+0] - km0[r];
                    float d1 = qm[g*3+1] - km1[r];
                    float d2 = qm[g*3+2] - km2[r];
                    float s00 = qs[g*6+0] + ks0[r];
                    float s01 = qs[g*6+1] + ks1[r];
                    float s02 = qs[g*6+2] + ks2[r];
                    float s11 = qs[g*6+3] + ks3[r];
                    float s12 = qs[g*6+4] + ks4[r];
                    float s22 = qs[g*6+5] + ks5[r];
                    float l00 = fmaxf(s00, 1e-8f);
                    float i00 = rsqrtf(l00);
                    float l10 = s01*i00, l20 = s02*i00;
                    float l11 = fmaxf(s11 - l10*l10, 1e-8f);
                    float i11 = rsqrtf(l11);
                    float l21 = (s12 - l20*l10)*i11;
                    float l22 = fmaxf(s22 - l20*l20 - l21*l21, 1e-8f);
                    float i22 = rsqrtf(l22);
                    float ld = __logf(l00) + __logf(l11) + __logf(l22);
                    float y0 = d0*i00;
                    float y1 = (d1 - l10*y0)*i11;
                    float y2 = (d2 - l20*y0 - l21*y1)*i22;
                    geo[r] += -0.5f*(y0*y0 + y1*y1 + y2*y2 + ld);
                }
            }
            f32x4 zb4 = *(const f32x4*)(zbg + ((size_t)bi*NH + h)*NN + j4);
            f32x4 mv  = *(const f32x4*)(mask + boff + j4);
            f32x4 lg;
            #pragma unroll
            for (int r = 0; r < 4; ++r) {
                float m2 = mI * mv[r];
                lg[r] = qk[r]*0.25f + zb4[r] + ascale*(geo[r]*m2) + hbias
                        + (1.f - m2)*(-100000.f);
            }
            *(f32x4*)&logits[h][j4] = lg;
        }
    }
    __syncthreads();

    // --- softmax per head (32 lanes per head) ---
    float mx = -3.4e38f;
    #pragma unroll
    for (int jj = 0; jj < 12; ++jj) mx = fmaxf(mx, logits[h][lnn + jj*32]);
    #pragma unroll
    for (int m = 16; m >= 1; m >>= 1) mx = fmaxf(mx, __shfl_xor(mx, m, 64));
    float se = 0.f;
    #pragma unroll
    for (int jj = 0; jj < 12; ++jj) {
        int j = lnn + jj*32;
        float e = __expf(logits[h][j] - mx);
        logits[h][j] = e;
        se += e;
    }
    #pragma unroll
    for (int m = 16; m >= 1; m >>= 1) se += __shfl_xor(se, m, 64);
    float inv = 1.f / se;
    float* cp = cat + (size_t)bi*640;

    // --- pass A: o[16], j-vectorized (f32x4) ---
    {
        float o[16];
        #pragma unroll
        for (int d = 0; d < 16; ++d) o[d] = 0.f;
        const float* vbase = vT + (size_t)(h*16)*BN + boff;
        #pragma unroll 1
        for (int jj = 0; jj < 3; ++jj) {
            int j4 = jj*128 + lnn*4;
            f32x4 lg4 = *(const f32x4*)&logits[h][j4];
            f32x4 w4;
            #pragma unroll
            for (int r = 0; r < 4; ++r) w4[r] = lg4[r] * inv;
            const float* vb = vbase + j4;
            #pragma unroll
            for (int d = 0; d < 16; ++d) {
                f32x4 kv = *(const f32x4*)(vb + (size_t)d*BN);
                #pragma unroll
                for (int r = 0; r < 4; ++r) o[d] = fmaf(w4[r], kv[r], o[d]);
            }
        }
        #pragma unroll
        for (int m = 16; m >= 1; m >>= 1) {
            #pragma unroll
            for (int d = 0; d < 16; ++d) o[d] += __shfl_xor(o[d], m, 64);
        }
        if (lnn == 0) {
            #pragma unroll
            for (int d = 0; d < 16; ++d) cp[h*16 + d] = o[d];
        }
    }

    // --- pass B: op[24] (value points) + local transform + norms, j-vectorized ---
    {
        float op[24];
        #pragma unroll
        for (int e = 0; e < 24; ++e) op[e] = 0.f;
        const float* gbase = vpgT + (size_t)(h*24)*BN + boff;
        #pragma unroll 1
        for (int jj = 0; jj < 3; ++jj) {
            int j4 = jj*128 + lnn*4;
            f32x4 lg4 = *(const f32x4*)&logits[h][j4];
            f32x4 w4;
            #pragma unroll
            for (int r = 0; r < 4; ++r) w4[r] = lg4[r] * inv;
            const float* gb = gbase + j4;
            #pragma unroll
            for (int e = 0; e < 24; ++e) {
                f32x4 gv = *(const f32x4*)(gb + (size_t)e*BN);
                #pragma unroll
                for (int r = 0; r < 4; ++r) op[e] = fmaf(w4[r], gv[r], op[e]);
            }
        }
        #pragma unroll
        for (int m = 16; m >= 1; m >>= 1) {
            #pragma unroll
            for (int e = 0; e < 24; ++e) op[e] += __shfl_xor(op[e], m, 64);
        }
        if (lnn == 0) {
            #pragma unroll
            for (int p = 0; p < 8; ++p) {
                float x  = op[p*3+0] - Tv[0];
                float y  = op[p*3+1] - Tv[1];
                float zz = op[p*3+2] - Tv[2];
                float l0 = Rm[0]*x + Rm[3]*y + Rm[6]*zz;   // R^T * (opt - trans)
                float l1 = Rm[1]*x + Rm[4]*y + Rm[7]*zz;
                float l2 = Rm[2]*x + Rm[5]*y + Rm[8]*zz;
                cp[128 + h*24 + p*3 + 0] = l0;
                cp[128 + h*24 + p*3 + 1] = l1;
                cp[128 + h*24 + p*3 + 2] = l2;
                cp[320 + h*8 + p] = sqrtf(l0*l0 + l1*l1 + l2*l2 + 1e-8f);
            }
        }
    }

    // --- pass C: opa[32] (pair projection), c-major half2, j-vectorized (4 half2/load) ---
    {
        float opa[32];
        #pragma unroll
        for (int c = 0; c < 32; ++c) opa[c] = 0.f;
        const __half2* pzb = (const __half2*)pzg2 + (size_t)bi*NN;
        #pragma unroll 1
        for (int jj = 0; jj < 3; ++jj) {
            int j4 = jj*128 + lnn*4;
            f32x4 lg4 = *(const f32x4*)&logits[h][j4];
            f32x4 w4;
            #pragma unroll
            for (int r = 0; r < 4; ++r) w4[r] = lg4[r] * inv;
            #pragma unroll
            for (int c2 = 0; c2 < 16; ++c2) {
                union { float4 f4; __half2 h2[4]; } u;
                u.f4 = *(const float4*)(pzb + (size_t)c2*PZROW + j4);
                #pragma unroll
                for (int r = 0; r < 4; ++r) {
                    float2 pf = __half22float2(u.h2[r]);
                    opa[2*c2]   = fmaf(w4[r], pf.x, opa[2*c2]);
                    opa[2*c2+1] = fmaf(w4[r], pf.y, opa[2*c2+1]);
                }
            }
        }
        #pragma unroll
        for (int m = 16; m >= 1; m >>= 1) {
            #pragma unroll
            for (int c = 0; c < 32; ++c) opa[c] += __shfl_xor(opa[c], m, 64);
        }
        if (lnn == 0) {
            #pragma unroll
            for (int c = 0; c < 32; ++c) cp[384 + h*32 + c] = opa[c];
        }
    }
}

// ---------------- K4: out = cat @ Wout + bout (8 rows/block: halves Wout re-reads) --
__global__ void __launch_bounds__(384)
k_out(const float* __restrict__ cat, const float* __restrict__ Wout,
      const float* __restrict__ bout, float* __restrict__ out) {
    __shared__ float cl[8][640];   // 20 KB
    int t  = threadIdx.x;
    int r0 = blockIdx.x * 8;
    for (int idx = t; idx < 8*640; idx += 384)
        cl[idx/640][idx%640] = cat[(size_t)(r0 + idx/640)*640 + (idx%640)];
    __syncthreads();
    int col = t;  // 384 threads == 384 cols
    float a[8];
    #pragma unroll
    for (int r = 0; r < 8; ++r) a[r] = 0.f;
    #pragma unroll 1
    for (int c = 0; c < 640; c += 2) {
        float w0 = Wout[(size_t)(c+0)*NCS + col];
        float w1 = Wout[(size_t)(c+1)*NCS + col];
        #pragma unroll
        for (int r = 0; r < 8; ++r) {
            a[r] = fmaf(cl[r][c+0], w0, a[r]);
            a[r] = fmaf(cl[r][c+1], w1, a[r]);
        }
    }
    float bv = bout[col];
    #pragma unroll
    for (int r = 0; r < 8; ++r)
        out[(size_t)(r0+r)*NCS + col] = a[r] + bv;
}

extern "C" void kernel_launch(void* const* d_in, const int* in_sizes, int n_in,
                              void* d_out, int out_size, void* d_ws, size_t ws_size,
                              hipStream_t stream) {
    const float* s    = (const float*)d_in[0];
    const float* z    = (const float*)d_in[1];
    const float* mask = (const float*)d_in[2];
    const float* rot  = (const float*)d_in[3];
    const float* trans= (const float*)d_in[4];
    const float* lm   = (const float*)d_in[5];
    const float* sc   = (const float*)d_in[6];
    const float* Wq   = (const float*)d_in[7];
    const float* Wk   = (const float*)d_in[8];
    const float* Wv   = (const float*)d_in[9];
    const float* Wb   = (const float*)d_in[10];
    const float* bb   = (const float*)d_in[11];
    const float* Wdz  = (const float*)d_in[12];
    const float* bdz  = (const float*)d_in[13];
    const float* Wqg  = (const float*)d_in[14];
    const float* bqg  = (const float*)d_in[15];
    const float* Wkg  = (const float*)d_in[16];
    const float* bkg  = (const float*)d_in[17];
    const float* Wvp  = (const float*)d_in[18];
    const float* bvp  = (const float*)d_in[19];
    const float* gsc  = (const float*)d_in[20];
    const float* gbi  = (const float*)d_in[21];
    const float* Wout = (const float*)d_in[22];
    const float* bout = (const float*)d_in[23];
    float* out = (float*)d_out;

    float* ws    = (float*)d_ws;
    float* lin   = ws;                    // 589824
    float* qmu   = lin   + 589824;        // 36864
    float* qsig  = qmu   + 36864;         // 73728
    float* kmuT  = qsig  + 73728;         // 36864
    float* ksigT = kmuT  + 36864;         // 73728
    float* vpgT  = ksigT + 73728;         // 147456
    float* kT    = vpgT  + 147456;        // 98304
    float* vT    = kT    + 98304;         // 98304
    float* cat   = vT    + 98304;         // 491520
    float* zbg   = cat   + 491520;        // 2359296
    __half* pzg2 = (__half*)(zbg + 2359296);        // 16*294912 half2 = 4718592 f32
    _Float16* wf = (_Float16*)((float*)pzg2 + 4718592);   // 6144 f16

    k_wprep<<<1, 256, 0, stream>>>(Wb, Wdz, wf);
    k_zrow<<<NRB + NZP, 256, 0, stream>>>(z, wf, bb, bdz, s,
                                          Wq, Wk, Wv, Wqg, bqg, Wkg, bkg, Wvp, bvp,
                                          zbg, pzg2, lin, kT, vT);
    k_geom<<<BN, 64, 0, stream>>>(lin, rot, trans, lm, sc, qmu, qsig, kmuT, ksigT, vpgT);
    k_attn2<<<BN, 256, 0, stream>>>(mask, rot, trans, lin, qmu, qsig, kmuT, ksigT,
                                    kT, vT, vpgT, zbg, pzg2, gsc, gbi, cat);
    k_out<<<96, 384, 0, stream>>>(cat, Wout, bout, out);
}

// Round 19
// 145.580 us; speedup vs baseline: 1.4067x; 1.4067x over previous
//
#include <hip/hip_runtime.h>
#include <hip/hip_fp16.h>

// InvariantGaussianAttention, MI355X (gfx950)
// B=2 N=384 CS=384 CZ=128 H=8 CH=16 G=2 P=8 CZ4=32
#define NB   2
#define NN   384
#define NCS  384
#define NCZ  128
#define NH   8
#define NCH  16
#define NG   2
#define NP   8
#define NCZ4 32
#define BN   (NB*NN)   // 768
#define LINW 768       // q(128)|k(128)|v(128)|qg(96)|kg(96)|vp(192)
#define PZROW ((size_t)BN*NN)   // 294912 half2 entries per c-pair row
#define NZP  1152      // persistent zproj blocks (4 chunks each)
#define NRB  288       // rowlin blocks, FIRST in grid

typedef _Float16 f16x8 __attribute__((ext_vector_type(8)));
typedef float    f32x4 __attribute__((ext_vector_type(4)));

typedef __attribute__((address_space(3))) char        as3_char;
typedef __attribute__((address_space(1))) const char  as1_char;
static __device__ __forceinline__ void gload_lds16(const void* g, void* l) {
    __builtin_amdgcn_global_load_lds((const as1_char*)g, (as3_char*)l, 16, 0, 0);
}

// ---------------- K0: build MFMA B-fragments of [Wb | Wdz | 0pad] (f16) -------------
__global__ void k_wprep(const float* __restrict__ Wb, const float* __restrict__ Wdz,
                        _Float16* __restrict__ wf) {
    int t = threadIdx.x;
    for (int e = t; e < 12*64*8; e += 256) {
        int r = e & 7, lane = (e >> 3) & 63, nk = e >> 9;
        int n = nk >> 2, kk = nk & 3;
        int c = kk*32 + (lane >> 4)*8 + r;
        int col = n*16 + (lane & 15);
        float w;
        if      (col < 8)  w = Wb[c*NH + col];
        else if (col < 40) w = Wdz[c*NCZ4 + (col-8)];
        else               w = 0.f;
        wf[e] = (_Float16)w;
    }
}

// per-iteration zproj body: fragments from zbuf, MFMA, scatter to outb, store.
static __device__ __forceinline__ void zchunk_body(
        const char* zbuf, char* outb, const f16x8* bfr,
        float b0, float b1, float b2,
        int t, int lane, int w, int ccol, int cjl, int bi, int ch,
        float* __restrict__ zbg, __half* __restrict__ pzg2) {
    float (*zbT)[64] = (float(*)[64])outb;
    __half (*pzt)[34] = (__half(*)[34])(outb + 2048);
    int row = w*16 + (lane & 15);
    int r7  = row & 7;
    const char* zrow_b = zbuf + row*512;
    f16x8 af[4];
    #pragma unroll
    for (int kk = 0; kk < 4; ++kk) {
        int u0 = ((lane >> 4) << 1) + kk*8;
        float4 lo = *(const float4*)(zrow_b + (((u0    ) ^ r7) << 4));
        float4 hi = *(const float4*)(zrow_b + (((u0 + 1) ^ r7) << 4));
        af[kk][0]=(_Float16)lo.x; af[kk][1]=(_Float16)lo.y;
        af[kk][2]=(_Float16)lo.z; af[kk][3]=(_Float16)lo.w;
        af[kk][4]=(_Float16)hi.x; af[kk][5]=(_Float16)hi.y;
        af[kk][6]=(_Float16)hi.z; af[kk][7]=(_Float16)hi.w;
    }
    f32x4 ac0 = {0.f,0.f,0.f,0.f}, ac1 = ac0, ac2 = ac0;
    ac0 = __builtin_amdgcn_mfma_f32_16x16x32_f16(af[0], bfr[0], ac0, 0,0,0);
    ac1 = __builtin_amdgcn_mfma_f32_16x16x32_f16(af[0], bfr[4], ac1, 0,0,0);
    ac2 = __builtin_amdgcn_mfma_f32_16x16x32_f16(af[0], bfr[8], ac2, 0,0,0);
    ac0 = __builtin_amdgcn_mfma_f32_16x16x32_f16(af[1], bfr[1], ac0, 0,0,0);
    ac1 = __builtin_amdgcn_mfma_f32_16x16x32_f16(af[1], bfr[5], ac1, 0,0,0);
    ac2 = __builtin_amdgcn_mfma_f32_16x16x32_f16(af[1], bfr[9], ac2, 0,0,0);
    ac0 = __builtin_amdgcn_mfma_f32_16x16x32_f16(af[2], bfr[2], ac0, 0,0,0);
    ac1 = __builtin_amdgcn_mfma_f32_16x16x32_f16(af[2], bfr[6], ac1, 0,0,0);
    ac2 = __builtin_amdgcn_mfma_f32_16x16x32_f16(af[2], bfr[10], ac2, 0,0,0);
    ac0 = __builtin_amdgcn_mfma_f32_16x16x32_f16(af[3], bfr[3], ac0, 0,0,0);
    ac1 = __builtin_amdgcn_mfma_f32_16x16x32_f16(af[3], bfr[7], ac1, 0,0,0);
    ac2 = __builtin_amdgcn_mfma_f32_16x16x32_f16(af[3], bfr[11], ac2, 0,0,0);
    #pragma unroll
    for (int r = 0; r < 4; ++r) {
        int j = cjl + r;
        float v0 = ac0[r] + b0;
        if (ccol < 8) zbT[ccol][j] = v0;
        else          pzt[j][ccol-8] = __float2half(v0);
        pzt[j][ccol+8] = __float2half(ac1[r] + b1);
        if (ccol < 8)
            pzt[j][ccol+24] = __float2half(ac2[r] + b2);
    }
    asm volatile("s_waitcnt lgkmcnt(0)" ::: "memory");
    __builtin_amdgcn_sched_barrier(0);
    __builtin_amdgcn_s_barrier();
    __builtin_amdgcn_sched_barrier(0);
    {   // zbT -> zbg[bi][h][ch*64 + j]
        int e = t*2, h = e >> 6, j = e & 63;
        float2 v; v.x = zbT[h][j]; v.y = zbT[h][j+1];
        *(float2*)(zbg + ((size_t)bi*NH + h)*NN + ch*64 + j) = v;
    }
    {   // pzt -> pzg2 (c-major half2, float4-packed)
        int cp = t >> 4, l = t & 15, j0 = l*4;
        union { __half2 h2[4]; float4 f4; } u;
        #pragma unroll
        for (int r = 0; r < 4; ++r) {
            int j = j0 + r;
            u.h2[r] = __halves2half2(pzt[j][2*cp], pzt[j][2*cp+1]);
        }
        __half2* dst = (__half2*)pzg2 + (size_t)cp*PZROW + (size_t)bi*NN + ch*64 + j0;
        *(float4*)dst = u.f4;
    }
}

static __device__ __forceinline__ void dma_chunk(const float* z, int c, int lane, int w,
                                                 char* dstbuf) {
    const char* nb = (const char*)(z + ((size_t)(c/6)*NN + (c%6)*64)*NCZ);
    #pragma unroll
    for (int i = 0; i < 8; ++i) {
        int o = (w*8 + i)*1024 + lane*16;
        int r = o >> 9;
        int u = (o >> 4) & 31;
        gload_lds16(nb + (r << 9) + ((u ^ (r & 7)) << 4), dstbuf + (w*8 + i)*1024);
    }
}

// ---------------- KA: role-switched { rowlin (0..287) | persistent DMA zproj } ------
__global__ void k_zrow(const float* __restrict__ z, const _Float16* __restrict__ wf,
       const float* __restrict__ bb, const float* __restrict__ bdz,
       const float* __restrict__ s,
       const float* __restrict__ Wq, const float* __restrict__ Wk,
       const float* __restrict__ Wv,
       const float* __restrict__ Wqg, const float* __restrict__ bqg,
       const float* __restrict__ Wkg, const float* __restrict__ bkg,
       const float* __restrict__ Wvp, const float* __restrict__ bvp,
       float* __restrict__ zbg, __half* __restrict__ pzg2,
       float* __restrict__ lin, float* __restrict__ kT, float* __restrict__ vT) {
    __shared__ __align__(16) char smem[78336];  // zsA 32K | zsB 32K | outA 6400 | outB 6400
    int t = threadIdx.x;

    if (blockIdx.x >= NRB) {
        // ================= persistent zproj, counted-vmcnt double buffer ==========
        int lane = t & 63, w = t >> 6;
        int ccol = lane & 15;
        int cjl  = w*16 + (lane >> 4)*4;
        int zbid = blockIdx.x - NRB;              // 0..1151

        dma_chunk(z, zbid, lane, w, smem);        // chunk 0 -> zsA

        f16x8 bfr[12];
        #pragma unroll
        for (int nk = 0; nk < 12; ++nk)
            bfr[nk] = ((const f16x8*)wf)[nk*64 + lane];
        float b0 = (ccol < 8) ? bb[ccol] : bdz[ccol - 8];
        float b1 = bdz[ccol + 8];
        float b2 = (ccol < 8) ? bdz[ccol + 24] : 0.f;

        // ---- iter 0: issue chunk1 -> zsB; wait only chunk0 (8 newer in flight) ----
        dma_chunk(z, zbid + NZP, lane, w, smem + 32768);
        asm volatile("s_waitcnt vmcnt(8)" ::: "memory");
        __builtin_amdgcn_sched_barrier(0);
        __builtin_amdgcn_s_barrier();
        __builtin_amdgcn_sched_barrier(0);
        zchunk_body(smem, smem + 65536, bfr, b0, b1, b2, t, lane, w, ccol, cjl,
                    zbid / 6, zbid % 6, zbg, pzg2);

        // ---- iter 1: issue chunk2 -> zsA; wait chunk1 (8 newer in flight) ----
        dma_chunk(z, zbid + 2*NZP, lane, w, smem);
        asm volatile("s_waitcnt vmcnt(8)" ::: "memory");
        __builtin_amdgcn_sched_barrier(0);
        __builtin_amdgcn_s_barrier();
        __builtin_amdgcn_sched_barrier(0);
        {
            int c = zbid + NZP;
            zchunk_body(smem + 32768, smem + 65536 + 6400, bfr, b0, b1, b2, t, lane, w,
                        ccol, cjl, c / 6, c % 6, zbg, pzg2);
        }

        // ---- iter 2: issue chunk3 -> zsB; wait chunk2 ----
        dma_chunk(z, zbid + 3*NZP, lane, w, smem + 32768);
        asm volatile("s_waitcnt vmcnt(8)" ::: "memory");
        __builtin_amdgcn_sched_barrier(0);
        __builtin_amdgcn_s_barrier();
        __builtin_amdgcn_sched_barrier(0);
        {
            int c = zbid + 2*NZP;
            zchunk_body(smem, smem + 65536, bfr, b0, b1, b2, t, lane, w,
                        ccol, cjl, c / 6, c % 6, zbg, pzg2);
        }

        // ---- iter 3: wait everything ----
        asm volatile("s_waitcnt vmcnt(0)" ::: "memory");
        __builtin_amdgcn_sched_barrier(0);
        __builtin_amdgcn_s_barrier();
        __builtin_amdgcn_sched_barrier(0);
        {
            int c = zbid + 3*NZP;
            zchunk_body(smem + 32768, smem + 65536 + 6400, bfr, b0, b1, b2, t, lane, w,
                        ccol, cjl, c / 6, c % 6, zbg, pzg2);
        }
    } else {
        // ================= rowlin (8 rows/block), 4x unrolled ILP =================
        float (*sl)[NCS] = (float(*)[NCS])smem;   // 12288 B
        int rb = blockIdx.x;                      // 0..287
        int r0 = (rb / 3) * 8;
        int col = (rb % 3) * 256 + t;
        for (int idx = t; idx < 8*NCS; idx += 256)
            sl[idx / NCS][idx % NCS] = s[(size_t)(r0 + idx/NCS)*NCS + (idx % NCS)];
        __syncthreads();
        const float* W; int sw; float bias = 0.f;
        if      (col < 128) { W = Wq  + col;        sw = 128; }
        else if (col < 256) { W = Wk  + (col-128);  sw = 128; }
        else if (col < 384) { W = Wv  + (col-256);  sw = 128; }
        else if (col < 480) { W = Wqg + (col-384);  sw = 96;  bias = bqg[col-384]; }
        else if (col < 576) { W = Wkg + (col-480);  sw = 96;  bias = bkg[col-480]; }
        else                { W = Wvp + (col-576);  sw = 192; bias = bvp[col-576]; }
        float a[8];
        #pragma unroll
        for (int r = 0; r < 8; ++r) a[r] = 0.f;
        #pragma unroll 1
        for (int c = 0; c < NCS; c += 4) {
            float w0 = W[(size_t)(c+0)*sw];
            float w1 = W[(size_t)(c+1)*sw];
            float w2 = W[(size_t)(c+2)*sw];
            float w3 = W[(size_t)(c+3)*sw];
            #pragma unroll
            for (int r = 0; r < 8; ++r) {
                a[r] = fmaf(sl[r][c+0], w0, a[r]);
                a[r] = fmaf(sl[r][c+1], w1, a[r]);
                a[r] = fmaf(sl[r][c+2], w2, a[r]);
                a[r] = fmaf(sl[r][c+3], w3, a[r]);
            }
        }
        #pragma unroll
        for (int r = 0; r < 8; ++r)
            lin[(size_t)(r0+r)*LINW + col] = a[r] + bias;
        if (col >= 128 && col < 384) {   // j-major panels for k_attn2
            f32x4 v0, v1;
            #pragma unroll
            for (int r = 0; r < 4; ++r) { v0[r] = a[r]; v1[r] = a[4+r]; }
            float* dst = (col < 256) ? (kT + (size_t)(col-128)*BN + r0)
                                     : (vT + (size_t)(col-256)*BN + r0);
            *(f32x4*)dst = v0;
            *(f32x4*)(dst+4) = v1;
        }
    }
}

// ---------------- K2: to_global; k-side + value points written j-major ----------------
__global__ void k_geom(const float* __restrict__ lin, const float* __restrict__ rot,
                       const float* __restrict__ trans, const float* __restrict__ lm,
                       const float* __restrict__ sc,
                       float* __restrict__ qmu, float* __restrict__ qsig,
                       float* __restrict__ kmuT, float* __restrict__ ksigT,
                       float* __restrict__ vpgT) {
    int bn = blockIdx.x, t = threadIdx.x;
    __shared__ float R[9], T[3], A[3], Bs[3];
    if (t < 9) R[t] = rot[bn*9 + t];
    if (t < 3) { T[t] = trans[bn*3+t]; A[t] = lm[bn*3+t]; Bs[t] = sc[bn*3+t]; }
    __syncthreads();
    {   // value points: one per thread (h=t/8, p=t&7), j-major out
        int h = t >> 3, p = t & 7;
        const float* vr = lin + (size_t)bn*LINW + 576 + h*24 + p*3;
        float x = vr[0], y = vr[1], z = vr[2];
        int e = h*24 + p*3;
        vpgT[(size_t)(e+0)*BN + bn] = R[0]*x + R[1]*y + R[2]*z + T[0];
        vpgT[(size_t)(e+1)*BN + bn] = R[3]*x + R[4]*y + R[5]*z + T[1];
        vpgT[(size_t)(e+2)*BN + bn] = R[6]*x + R[7]*y + R[8]*z + T[2];
    }
    if (t < 32) {
        int side = t >> 4, item = t & 15;      // item = h*2+g
        const float* raw = lin + (size_t)bn*LINW + (side ? 480 : 384) + item*6;
        float u0 = tanhf(raw[0])*3.f, u1 = tanhf(raw[1])*3.f, u2 = tanhf(raw[2])*3.f;
        float e0 = Bs[0] + tanhf(raw[3])*2.f;
        float e1 = Bs[1] + tanhf(raw[4])*2.f;
        float e2 = Bs[2] + tanhf(raw[5])*2.f;
        float sl0 = fmaxf(expf(e0), 1e-6f);
        float sl1 = fmaxf(expf(e1), 1e-6f);
        float sl2 = fmaxf(expf(e2), 1e-6f);
        float p0 = A[0] + u0*sl0, p1 = A[1] + u1*sl1, p2 = A[2] + u2*sl2;
        float mu0 = R[0]*p0 + R[1]*p1 + R[2]*p2 + T[0];
        float mu1 = R[3]*p0 + R[4]*p1 + R[5]*p2 + T[1];
        float mu2 = R[6]*p0 + R[7]*p1 + R[8]*p2 + T[2];
        float v0 = expf(2.f*e0), v1 = expf(2.f*e1), v2 = expf(2.f*e2);
        float s00 = R[0]*R[0]*v0 + R[1]*R[1]*v1 + R[2]*R[2]*v2;
        float s01 = R[0]*R[3]*v0 + R[1]*R[4]*v1 + R[2]*R[5]*v2;
        float s02 = R[0]*R[6]*v0 + R[1]*R[7]*v1 + R[2]*R[8]*v2;
        float s11 = R[3]*R[3]*v0 + R[4]*R[4]*v1 + R[5]*R[5]*v2;
        float s12 = R[3]*R[6]*v0 + R[4]*R[7]*v1 + R[5]*R[8]*v2;
        float s22 = R[6]*R[6]*v0 + R[7]*R[7]*v1 + R[8]*R[8]*v2;
        if (side) {   // k-side: j-major
            kmuT[(size_t)(item*3+0)*BN + bn] = mu0;
            kmuT[(size_t)(item*3+1)*BN + bn] = mu1;
            kmuT[(size_t)(item*3+2)*BN + bn] = mu2;
            ksigT[(size_t)(item*6+0)*BN + bn] = s00;
            ksigT[(size_t)(item*6+1)*BN + bn] = s01;
            ksigT[(size_t)(item*6+2)*BN + bn] = s02;
            ksigT[(size_t)(item*6+3)*BN + bn] = s11;
            ksigT[(size_t)(item*6+4)*BN + bn] = s12;
            ksigT[(size_t)(item*6+5)*BN + bn] = s22;
        } else {      // q-side: row-major (per-block broadcast read)
            float* mud = qmu + (size_t)bn*48 + item*3;
            mud[0]=mu0; mud[1]=mu1; mud[2]=mu2;
            float* sgd = qsig + (size_t)bn*96 + item*6;
            sgd[0]=s00; sgd[1]=s01; sgd[2]=s02; sgd[3]=s11; sgd[4]=s12; sgd[5]=s22;
        }
    }
}

// ---------------- K3: attention (no z), one block per (b,i), j-vectorized passes ----
__global__ void __launch_bounds__(256, 2)
k_attn2(const float* __restrict__ mask,
        const float* __restrict__ rot, const float* __restrict__ trans,
        const float* __restrict__ lin,
        const float* __restrict__ qmu, const float* __restrict__ qsig,
        const float* __restrict__ kmuT, const float* __restrict__ ksigT,
        const float* __restrict__ kT, const float* __restrict__ vT,
        const float* __restrict__ vpgT,
        const float* __restrict__ zbg, const __half* __restrict__ pzg2,
        const float* __restrict__ gsc, const float* __restrict__ gbi,
        float* __restrict__ cat) {
    __shared__ float  logits[NH][NN];   // 12 KB
    __shared__ float  qrow[128];
    __shared__ float  qmu_s[48], qsig_s[96];
    __shared__ float  Rm[9], Tv[3];
    __shared__ float  aH[NH], bH[NH];
    __shared__ float  maskI;

    int t  = threadIdx.x;
    int b  = blockIdx.x / NN, i = blockIdx.x % NN;
    int bi = b*NN + i;
    const size_t boff = (size_t)b*NN;

    if (t < 128) qrow[t] = lin[(size_t)bi*LINW + t];
    if (t < 48)  qmu_s[t] = qmu[(size_t)bi*48 + t];
    if (t >= 64 && t < 160) qsig_s[t-64] = qsig[(size_t)bi*96 + (t-64)];
    if (t >= 160 && t < 169) Rm[t-160] = rot[bi*9 + (t-160)];
    if (t >= 169 && t < 172) Tv[t-169] = trans[bi*3 + (t-169)];
    if (t >= 176 && t < 184) {
        int h = t-176;
        float x = gsc[h];
        aH[h] = (x > 20.f) ? x : log1pf(expf(x));
        bH[h] = gbi[h];
    }
    if (t == 255) maskI = mask[bi];
    __syncthreads();

    // ---- phase 0: qk + geo NLL + zb + mask; j-quad mapping, coalesced ----
    int h = t >> 5, lnn = t & 31;
    {
        float qv[16];
        #pragma unroll
        for (int d = 0; d < 16; ++d) qv[d] = qrow[h*16 + d];
        float qm[6], qs[12];
        #pragma unroll
        for (int e = 0; e < 6; ++e)  qm[e] = qmu_s[h*6 + e];
        #pragma unroll
        for (int e = 0; e < 12; ++e) qs[e] = qsig_s[h*12 + e];
        float ascale = aH[h], hbias = bH[h], mI = maskI;
        #pragma unroll 1
        for (int jj = 0; jj < 3; ++jj) {
            int j4 = jj*128 + lnn*4;
            const float* kp = kT + (size_t)(h*16)*BN + boff + j4;
            f32x4 qk = {0.f,0.f,0.f,0.f};
            #pragma unroll
            for (int d = 0; d < 16; ++d) {
                f32x4 kv = *(const f32x4*)(kp + (size_t)d*BN);
                #pragma unroll
                for (int r = 0; r < 4; ++r) qk[r] = fmaf(qv[d], kv[r], qk[r]);
            }
            f32x4 geo = {0.f,0.f,0.f,0.f};
            #pragma unroll
            for (int g = 0; g < NG; ++g) {
                const float* kmb = kmuT + (size_t)((h*2+g)*3)*BN + boff + j4;
                f32x4 km0 = *(const f32x4*)(kmb);
                f32x4 km1 = *(const f32x4*)(kmb + BN);
                f32x4 km2 = *(const f32x4*)(kmb + 2*BN);
                const float* ksb = ksigT + (size_t)((h*2+g)*6)*BN + boff + j4;
                f32x4 ks0 = *(const f32x4*)(ksb);
                f32x4 ks1 = *(const f32x4*)(ksb + BN);
                f32x4 ks2 = *(const f32x4*)(ksb + 2*BN);
                f32x4 ks3 = *(const f32x4*)(ksb + 3*BN);
                f32x4 ks4 = *(const f32x4*)(ksb + 4*BN);
                f32x4 ks5 = *(const f32x4*)(ksb + 5*BN);
                #pragma unroll
                for (int r = 0; r < 4; ++r) {
                    float d0 = qm[g*3+0] - km0[r];
                    float d1 = qm[g*3+1] - km1[r];
                    float d2 = qm[g*3+2] - km2[r];
                    float s00 = qs[g*6+0] + ks0[r];
                    float s01 = qs[g*6+1] + ks1[r];
                    float s02 = qs[g*6+2] + ks2[r];
                    float s11 = qs[g*6+3] + ks3[r];
                    float s12 = qs[g*6+4] + ks4[r];
                    float s22 = qs[g*6+5] + ks5[r];
                    float l00 = fmaxf(s00, 1e-8f);
                    float i00 = rsqrtf(l00);
                    float l10 = s01*i00, l20 = s02*i00;
                    float l11 = fmaxf(s11 - l10*l10, 1e-8f);
                    float i11 = rsqrtf(l11);
                    float l21 = (s12 - l20*l10)*i11;
                    float l22 = fmaxf(s22 - l20*l20 - l21*l21, 1e-8f);
                    float i22 = rsqrtf(l22);
                    float ld = __logf(l00) + __logf(l11) + __logf(l22);
                    float y0 = d0*i00;
                    float y1 = (d1 - l10*y0)*i11;
                    float y2 = (d2 - l20*y0 - l21*y1)*i22;
                    geo[r] += -0.5f*(y0*y0 + y1*y1 + y2*y2 + ld);
                }
            }
            f32x4 zb4 = *(const f32x4*)(zbg + ((size_t)bi*NH + h)*NN + j4);
            f32x4 mv  = *(const f32x4*)(mask + boff + j4);
            f32x4 lg;
            #pragma unroll
            for (int r = 0; r < 4; ++r) {
                float m2 = mI * mv[r];
                lg[r] = qk[r]*0.25f + zb4[r] + ascale*(geo[r]*m2) + hbias
                        + (1.f - m2)*(-100000.f);
            }
            *(f32x4*)&logits[h][j4] = lg;
        }
    }
    __syncthreads();

    // --- softmax per head (32 lanes per head) ---
    float mx = -3.4e38f;
    #pragma unroll
    for (int jj = 0; jj < 12; ++jj) mx = fmaxf(mx, logits[h][lnn + jj*32]);
    #pragma unroll
    for (int m = 16; m >= 1; m >>= 1) mx = fmaxf(mx, __shfl_xor(mx, m, 64));
    float se = 0.f;
    #pragma unroll
    for (int jj = 0; jj < 12; ++jj) {
        int j = lnn + jj*32;
        float e = __expf(logits[h][j] - mx);
        logits[h][j] = e;
        se += e;
    }
    #pragma unroll
    for (int m = 16; m >= 1; m >>= 1) se += __shfl_xor(se, m, 64);
    float inv = 1.f / se;
    float* cp = cat + (size_t)bi*640;

    // --- pass A: o[16], j-vectorized (f32x4) ---
    {
        float o[16];
        #pragma unroll
        for (int d = 0; d < 16; ++d) o[d] = 0.f;
        const float* vbase = vT + (size_t)(h*16)*BN + boff;
        #pragma unroll 1
        for (int jj = 0; jj < 3; ++jj) {
            int j4 = jj*128 + lnn*4;
            f32x4 lg4 = *(const f32x4*)&logits[h][j4];
            f32x4 w4;
            #pragma unroll
            for (int r = 0; r < 4; ++r) w4[r] = lg4[r] * inv;
            const float* vb = vbase + j4;
            #pragma unroll
            for (int d = 0; d < 16; ++d) {
                f32x4 kv = *(const f32x4*)(vb + (size_t)d*BN);
                #pragma unroll
                for (int r = 0; r < 4; ++r) o[d] = fmaf(w4[r], kv[r], o[d]);
            }
        }
        #pragma unroll
        for (int m = 16; m >= 1; m >>= 1) {
            #pragma unroll
            for (int d = 0; d < 16; ++d) o[d] += __shfl_xor(o[d], m, 64);
        }
        if (lnn == 0) {
            #pragma unroll
            for (int d = 0; d < 16; ++d) cp[h*16 + d] = o[d];
        }
    }

    // --- pass B: op[24] (value points) + local transform + norms, j-vectorized ---
    {
        float op[24];
        #pragma unroll
        for (int e = 0; e < 24; ++e) op[e] = 0.f;
        const float* gbase = vpgT + (size_t)(h*24)*BN + boff;
        #pragma unroll 1
        for (int jj = 0; jj < 3; ++jj) {
            int j4 = jj*128 + lnn*4;
            f32x4 lg4 = *(const f32x4*)&logits[h][j4];
            f32x4 w4;
            #pragma unroll
            for (int r = 0; r < 4; ++r) w4[r] = lg4[r] * inv;
            const float* gb = gbase + j4;
            #pragma unroll
            for (int e = 0; e < 24; ++e) {
                f32x4 gv = *(const f32x4*)(gb + (size_t)e*BN);
                #pragma unroll
                for (int r = 0; r < 4; ++r) op[e] = fmaf(w4[r], gv[r], op[e]);
            }
        }
        #pragma unroll
        for (int m = 16; m >= 1; m >>= 1) {
            #pragma unroll
            for (int e = 0; e < 24; ++e) op[e] += __shfl_xor(op[e], m, 64);
        }
        if (lnn == 0) {
            #pragma unroll
            for (int p = 0; p < 8; ++p) {
                float x  = op[p*3+0] - Tv[0];
                float y  = op[p*3+1] - Tv[1];
                float zz = op[p*3+2] - Tv[2];
                float l0 = Rm[0]*x + Rm[3]*y + Rm[6]*zz;   // R^T * (opt - trans)
                float l1 = Rm[1]*x + Rm[4]*y + Rm[7]*zz;
                float l2 = Rm[2]*x + Rm[5]*y + Rm[8]*zz;
                cp[128 + h*24 + p*3 + 0] = l0;
                cp[128 + h*24 + p*3 + 1] = l1;
                cp[128 + h*24 + p*3 + 2] = l2;
                cp[320 + h*8 + p] = sqrtf(l0*l0 + l1*l1 + l2*l2 + 1e-8f);
            }
        }
    }

    // --- pass C: opa[32] (pair projection), c-major half2, j-vectorized (4 half2/load) ---
    {
        float opa[32];
        #pragma unroll
        for (int c = 0; c < 32; ++c) opa[c] = 0.f;
        const __half2* pzb = (const __half2*)pzg2 + (size_t)bi*NN;
        #pragma unroll 1
        for (int jj = 0; jj < 3; ++jj) {
            int j4 = jj*128 + lnn*4;
            f32x4 lg4 = *(const f32x4*)&logits[h][j4];
            f32x4 w4;
            #pragma unroll
            for (int r = 0; r < 4; ++r) w4[r] = lg4[r] * inv;
            #pragma unroll
            for (int c2 = 0; c2 < 16; ++c2) {
                union { float4 f4; __half2 h2[4]; } u;
                u.f4 = *(const float4*)(pzb + (size_t)c2*PZROW + j4);
                #pragma unroll
                for (int r = 0; r < 4; ++r) {
                    float2 pf = __half22float2(u.h2[r]);
                    opa[2*c2]   = fmaf(w4[r], pf.x, opa[2*c2]);
                    opa[2*c2+1] = fmaf(w4[r], pf.y, opa[2*c2+1]);
                }
            }
        }
        #pragma unroll
        for (int m = 16; m >= 1; m >>= 1) {
            #pragma unroll
            for (int c = 0; c < 32; ++c) opa[c] += __shfl_xor(opa[c], m, 64);
        }
        if (lnn == 0) {
            #pragma unroll
            for (int c = 0; c < 32; ++c) cp[384 + h*32 + c] = opa[c];
        }
    }
}

// ---------------- K4: out = cat @ Wout + bout (192 blocks x 4 rows, measured-best) --
__global__ void k_out(const float* __restrict__ cat, const float* __restrict__ Wout,
                      const float* __restrict__ bout, float* __restrict__ out) {
    __shared__ float cl[4][640];
    int t  = threadIdx.x;
    int r0 = blockIdx.x * 4;
    for (int idx = t; idx < 4*640; idx += 384)
        cl[idx/640][idx%640] = cat[(size_t)(r0 + idx/640)*640 + (idx%640)];
    __syncthreads();
    int col = t;  // 384 threads == 384 cols
    float a0=0.f, a1=0.f, a2=0.f, a3=0.f;
    for (int c = 0; c < 640; ++c) {
        float w = Wout[(size_t)c*NCS + col];
        a0 = fmaf(cl[0][c], w, a0);
        a1 = fmaf(cl[1][c], w, a1);
        a2 = fmaf(cl[2][c], w, a2);
        a3 = fmaf(cl[3][c], w, a3);
    }
    float bv = bout[col];
    out[(size_t)(r0+0)*NCS + col] = a0 + bv;
    out[(size_t)(r0+1)*NCS + col] = a1 + bv;
    out[(size_t)(r0+2)*NCS + col] = a2 + bv;
    out[(size_t)(r0+3)*NCS + col] = a3 + bv;
}

extern "C" void kernel_launch(void* const* d_in, const int* in_sizes, int n_in,
                              void* d_out, int out_size, void* d_ws, size_t ws_size,
                              hipStream_t stream) {
    const float* s    = (const float*)d_in[0];
    const float* z    = (const float*)d_in[1];
    const float* mask = (const float*)d_in[2];
    const float* rot  = (const float*)d_in[3];
    const float* trans= (const float*)d_in[4];
    const float* lm   = (const float*)d_in[5];
    const float* sc   = (const float*)d_in[6];
    const float* Wq   = (const float*)d_in[7];
    const float* Wk   = (const float*)d_in[8];
    const float* Wv   = (const float*)d_in[9];
    const float* Wb   = (const float*)d_in[10];
    const float* bb   = (const float*)d_in[11];
    const float* Wdz  = (const float*)d_in[12];
    const float* bdz  = (const float*)d_in[13];
    const float* Wqg  = (const float*)d_in[14];
    const float* bqg  = (const float*)d_in[15];
    const float* Wkg  = (const float*)d_in[16];
    const float* bkg  = (const float*)d_in[17];
    const float* Wvp  = (const float*)d_in[18];
    const float* bvp  = (const float*)d_in[19];
    const float* gsc  = (const float*)d_in[20];
    const float* gbi  = (const float*)d_in[21];
    const float* Wout = (const float*)d_in[22];
    const float* bout = (const float*)d_in[23];
    float* out = (float*)d_out;

    float* ws    = (float*)d_ws;
    float* lin   = ws;                    // 589824
    float* qmu   = lin   + 589824;        // 36864
    float* qsig  = qmu   + 36864;         // 73728
    float* kmuT  = qsig  + 73728;         // 36864
    float* ksigT = kmuT  + 36864;         // 73728
    float* vpgT  = ksigT + 73728;         // 147456
    float* kT    = vpgT  + 147456;        // 98304
    float* vT    = kT    + 98304;         // 98304
    float* cat   = vT    + 98304;         // 491520
    float* zbg   = cat   + 491520;        // 2359296
    __half* pzg2 = (__half*)(zbg + 2359296);        // 16*294912 half2 = 4718592 f32
    _Float16* wf = (_Float16*)((float*)pzg2 + 4718592);   // 6144 f16

    k_wprep<<<1, 256, 0, stream>>>(Wb, Wdz, wf);
    k_zrow<<<NRB + NZP, 256, 0, stream>>>(z, wf, bb, bdz, s,
                                          Wq, Wk, Wv, Wqg, bqg, Wkg, bkg, Wvp, bvp,
                                          zbg, pzg2, lin, kT, vT);
    k_geom<<<BN, 64, 0, stream>>>(lin, rot, trans, lm, sc, qmu, qsig, kmuT, ksigT, vpgT);
    k_attn2<<<BN, 256, 0, stream>>>(mask, rot, trans, lin, qmu, qsig, kmuT, ksigT,
                                    kT, vT, vpgT, zbg, pzg2, gsc, gbi, cat);
    k_out<<<192, 384, 0, stream>>>(cat, Wout, bout, out);
}